// Round 7
// baseline (274.559 us; speedup 1.0000x reference)
//
#include <hip/hip_runtime.h>
#include <stdint.h>

#define MDIM 16384
#define NDIM 1020
#define KDIM 2048
#define NPAD 1024
#define TK   (KDIM / 64)   // 32 K-tiles of BK=64

typedef __attribute__((ext_vector_type(4))) float f32x4;
typedef __attribute__((ext_vector_type(8))) short short8;

#define MFMA16(a, b, c) __builtin_amdgcn_mfma_f32_16x16x32_bf16((a), (b), (c), 0, 0, 0)

// asm ds_read_b128 with register-only constraints; waits issued manually via
// counted lgkmcnt (DS ops retire in order -> counted waits are exact).
template <int OFF>
static __device__ __forceinline__ short8 dsr(unsigned addr) {
    short8 r;
    asm volatile("ds_read_b128 %0, %1 offset:%2" : "=v"(r) : "v"(addr), "i"(OFF));
    return r;
}

// rule 18: every wait is followed by sched_barrier(0).
#define LGKM(N)                                                       \
    asm volatile("s_waitcnt lgkmcnt(" #N ")" ::: "memory");           \
    __builtin_amdgcn_sched_barrier(0);

// rule 17: keep a value live (and its producing asm ds_read meaningful)
// without any consuming instruction.
#define SINK(x) asm volatile("" :: "v"(x))

// f32 -> bf16 round-to-nearest-even
__device__ __forceinline__ unsigned short f2bf(float f) {
    unsigned int u = __float_as_uint(f);
    unsigned int r = (u + 0x7FFFu + ((u >> 16) & 1u)) >> 16;
    return (unsigned short)r;
}

// ---------------------------------------------------------------------------
// Kernel 1: W [K=2048][N=1020] f32 -> Wt [NPAD=1024][K=2048] bf16 (transposed)
// ---------------------------------------------------------------------------
__global__ void prep_w_kernel(const float* __restrict__ W,
                              unsigned short* __restrict__ Wt) {
    const int id = blockIdx.x * 256 + threadIdx.x;  // 512 blocks * 256
    const int n0 = (id & 255) * 4;
    const int k0 = (id >> 8) * 4;
    float a[4][4];
    if (n0 < NDIM) {
#pragma unroll
        for (int i = 0; i < 4; ++i) {
            const float* p = W + (size_t)(k0 + i) * NDIM + n0;
            a[i][0] = p[0]; a[i][1] = p[1]; a[i][2] = p[2]; a[i][3] = p[3];
        }
    } else {
#pragma unroll
        for (int i = 0; i < 4; ++i)
#pragma unroll
            for (int j = 0; j < 4; ++j) a[i][j] = 0.f;
    }
#pragma unroll
    for (int j = 0; j < 4; ++j) {
        uint2 p;
        p.x = (unsigned)f2bf(a[0][j]) | ((unsigned)f2bf(a[1][j]) << 16);
        p.y = (unsigned)f2bf(a[2][j]) | ((unsigned)f2bf(a[3][j]) << 16);
        *(uint2*)(Wt + (size_t)(n0 + j) * KDIM + k0) = p;
    }
}

// ---------------------------------------------------------------------------
// Kernel 1b: x [M][K] f32 -> Xb [M][K] bf16
// ---------------------------------------------------------------------------
__global__ void prep_x_kernel(const float* __restrict__ x,
                              unsigned short* __restrict__ Xb) {
    const size_t total = (size_t)MDIM * KDIM;
    const size_t stride = (size_t)gridDim.x * 256 * 8;
    for (size_t i = ((size_t)blockIdx.x * 256 + threadIdx.x) * 8; i < total; i += stride) {
        const float4 v0 = *(const float4*)(x + i);
        const float4 v1 = *(const float4*)(x + i + 4);
        uint4 p;
        p.x = (unsigned)f2bf(v0.x) | ((unsigned)f2bf(v0.y) << 16);
        p.y = (unsigned)f2bf(v0.z) | ((unsigned)f2bf(v0.w) << 16);
        p.z = (unsigned)f2bf(v1.x) | ((unsigned)f2bf(v1.y) << 16);
        p.w = (unsigned)f2bf(v1.z) | ((unsigned)f2bf(v1.w) << 16);
        *(uint4*)(Xb + i) = p;
    }
}

// ---------------------------------------------------------------------------
// Kernel 2 (template): R6 structure, with ablation variants.
//   V=0: real kernel (identical schedule to R6).
//   V=1: noMFMA — every memory/sync op identical (ds_read, STAGE, barriers,
//        lgkm/vmcnt), MFMAs removed, frags kept live via asm sinks.
// TKMUL: K-loop length multiplier (k index wraps) so the ablation's duration
// exceeds the real gemm's and lands in the rocprof top-5 table.
// ---------------------------------------------------------------------------
template <int V, int TKMUL>
__global__ __launch_bounds__(512, 2) void gemm_abl(
    const unsigned short* __restrict__ Xb,
    const unsigned short* __restrict__ Wt,
    const float* __restrict__ bias,
    float* __restrict__ out) {
    extern __shared__ unsigned short lds_raw[];  // 2 bufs x (A 256x64 + B 256x64)

    constexpr bool HAS_MFMA = (V != 1);

    const int tid  = threadIdx.x;
    const int lane = tid & 63;
    const int wid  = tid >> 6;   // 0..7
    const int wr   = wid >> 2;   // 0..1 (M)
    const int wc   = wid & 3;    // 0..3 (N)

    // XCD-aware swizzle: 256 blocks, 8 XCDs, 32 consecutive per XCD
    const int bid = blockIdx.x;
    const int swz = (bid & 7) * 32 + (bid >> 3);
    const int bm  = swz >> 2;    // 0..63
    const int bn  = swz & 3;     // 0..3

    // per-lane pre-swizzled staging source (rule 21)
    const int srow = wid * 8 + (lane >> 3);
    const int scb  = ((lane & 7) ^ (lane >> 3)) * 8;
    const unsigned short* aS = Xb + (size_t)(bm * 256 + srow) * KDIM + scb;
    const unsigned short* bS = Wt + (size_t)(bn * 256 + srow) * KDIM + scb;

#define STAGE(BUFI, OP, STRIPE, S) do {                                          \
    const size_t ks_ = (size_t)(((S) * 64) & (KDIM - 1));                        \
    const unsigned short* sp_ =                                                  \
        ((OP) ? bS : aS) + (size_t)((STRIPE) * 64) * KDIM + ks_;                 \
    __builtin_amdgcn_global_load_lds(                                            \
        (const __attribute__((address_space(1))) unsigned int*)sp_,              \
        (__attribute__((address_space(3))) unsigned int*)(lds_raw +              \
            (BUFI) * 32768 + (OP) * 16384 + ((STRIPE) * 64 + wid * 8) * 64),     \
        16, 0, 0);                                                              \
} while (0)

    // LDS read addressing (verified R3/R4)
    const unsigned ldsbase =
        (unsigned)(uintptr_t)(__attribute__((address_space(3))) unsigned short*)lds_raw;
    const unsigned l15 = lane & 15, hi = lane >> 4, l7 = lane & 7;
    const unsigned c0 = (unsigned)((0 * 4 + hi) ^ l7) << 4;
    const unsigned c1 = (unsigned)((1 * 4 + hi) ^ l7) << 4;
    const unsigned pbA = ldsbase + (unsigned)(wr * 128 + l15) * 128;
    const unsigned pbB = ldsbase + 32768u + (unsigned)(wc * 64 + l15) * 128;
    const unsigned aA0_0 = pbA + c0,          aA0_1 = pbA + c1;
    const unsigned aA1_0 = pbA + 65536u + c0, aA1_1 = pbA + 65536u + c1;
    const unsigned bB0_0 = pbB + c0,          bB0_1 = pbB + c1;
    const unsigned bB1_0 = pbB + 65536u + c0, bB1_1 = pbB + 65536u + c1;

    f32x4 acc[8][4];
#pragma unroll
    for (int i = 0; i < 8; ++i)
#pragma unroll
        for (int j = 0; j < 4; ++j) {
            f32x4 z = {0.f, 0.f, 0.f, 0.f};
            acc[i][j] = z;
        }

    short8 af0[8], af1[8];   // A frags @k2=0 / @k2=1
    short8 bfv[4][2];        // B frags [nf][k2]

#define RB(BUF, K)                                                    \
    bfv[0][K] = dsr<0 * 2048>(bB##BUF##_##K);                         \
    bfv[1][K] = dsr<1 * 2048>(bB##BUF##_##K);                         \
    bfv[2][K] = dsr<2 * 2048>(bB##BUF##_##K);                         \
    bfv[3][K] = dsr<3 * 2048>(bB##BUF##_##K);

#define RA(BUF, K, MF) af##K[MF] = dsr<(MF) * 2048>(aA##BUF##_##K);

#define G(K, MF, LG)                                                  \
    LGKM(LG)                                                          \
    if constexpr (HAS_MFMA) {                                         \
        __builtin_amdgcn_s_setprio(1);                                \
        acc[MF][0] = MFMA16(af##K[MF], bfv[0][K], acc[MF][0]);        \
        acc[MF][1] = MFMA16(af##K[MF], bfv[1][K], acc[MF][1]);        \
        acc[MF][2] = MFMA16(af##K[MF], bfv[2][K], acc[MF][2]);        \
        acc[MF][3] = MFMA16(af##K[MF], bfv[3][K], acc[MF][3]);        \
        __builtin_amdgcn_s_setprio(0);                                \
    } else {                                                          \
        SINK(af##K[MF]);                                              \
    }

#define TILE(T, BUF)                                                            \
  {                                                                             \
    RB(BUF, 0)                                       /* idx 0-3   */           \
    RA(BUF, 0, 0) RA(BUF, 0, 1) RA(BUF, 0, 2) RA(BUF, 0, 3)                     \
    RA(BUF, 0, 4) RA(BUF, 0, 5) RA(BUF, 0, 6) RA(BUF, 0, 7) /* idx 4-11 */      \
    RB(BUF, 1)                                       /* idx 12-15 */           \
    G(0, 0, 11) G(0, 1, 10) G(0, 2, 9) G(0, 3, 8) G(0, 4, 7) G(0, 5, 6)         \
    RA(BUF, 1, 0) RA(BUF, 1, 1) RA(BUF, 1, 2) RA(BUF, 1, 3)                     \
    RA(BUF, 1, 4) RA(BUF, 1, 5) RA(BUF, 1, 6) RA(BUF, 1, 7) /* idx 16-23 */     \
    G(0, 6, 13) G(0, 7, 12)                                                     \
    G(1, 0, 7) G(1, 1, 6) G(1, 2, 5) G(1, 3, 4)                                 \
    G(1, 4, 3) G(1, 5, 2) G(1, 6, 1) G(1, 7, 0)                                 \
    if constexpr (!HAS_MFMA) {                                                  \
        SINK(bfv[0][0]); SINK(bfv[1][0]); SINK(bfv[2][0]); SINK(bfv[3][0]);     \
        SINK(bfv[0][1]); SINK(bfv[1][1]); SINK(bfv[2][1]); SINK(bfv[3][1]);     \
    }                                                                           \
    __builtin_amdgcn_s_barrier();  /* all waves' reads done -> WAR-safe */      \
    STAGE(BUF, 0, 0, (T) + 2); STAGE(BUF, 0, 1, (T) + 2);                       \
    STAGE(BUF, 0, 2, (T) + 2); STAGE(BUF, 0, 3, (T) + 2);                       \
    STAGE(BUF, 1, 0, (T) + 2); STAGE(BUF, 1, 1, (T) + 2);                       \
    STAGE(BUF, 1, 2, (T) + 2); STAGE(BUF, 1, 3, (T) + 2);                       \
    asm volatile("s_waitcnt vmcnt(8)" ::: "memory"); /* t+1 fully landed */     \
    __builtin_amdgcn_sched_barrier(0);                                          \
    __builtin_amdgcn_s_barrier();                                               \
  }

    // ---- prologue: stage tile0 -> buf0, tile1 -> buf1; wait tile0 ----
    STAGE(0, 0, 0, 0); STAGE(0, 0, 1, 0); STAGE(0, 0, 2, 0); STAGE(0, 0, 3, 0);
    STAGE(0, 1, 0, 0); STAGE(0, 1, 1, 0); STAGE(0, 1, 2, 0); STAGE(0, 1, 3, 0);
    STAGE(1, 0, 0, 1); STAGE(1, 0, 1, 1); STAGE(1, 0, 2, 1); STAGE(1, 0, 3, 1);
    STAGE(1, 1, 0, 1); STAGE(1, 1, 1, 1); STAGE(1, 1, 2, 1); STAGE(1, 1, 3, 1);
    asm volatile("s_waitcnt vmcnt(8)" ::: "memory");  // tile0 landed
    __builtin_amdgcn_sched_barrier(0);
    __builtin_amdgcn_s_barrier();

    for (int t2 = 0; t2 < TK * TKMUL; t2 += 2) {
        TILE(t2, 0)
        TILE(t2 + 1, 1)
    }

    // ---- epilogue ----
    if constexpr (V == 0) {
#pragma unroll
        for (int nf = 0; nf < 4; ++nf) {
            const int col = bn * 256 + wc * 64 + nf * 16 + (lane & 15);
            if (col < NDIM) {
                const float bv = bias[col];
#pragma unroll
                for (int mf = 0; mf < 8; ++mf) {
                    const int row = bm * 256 + wr * 128 + mf * 16 + ((lane >> 4) << 2);
                    float* op = out + (size_t)row * NDIM + col;
#pragma unroll
                    for (int r = 0; r < 4; ++r)
                        op[(size_t)r * NDIM] = acc[mf][nf][r] + bv;
                }
            }
        }
    } else {
#pragma unroll
        for (int mf = 0; mf < 8; ++mf)
#pragma unroll
            for (int nf = 0; nf < 4; ++nf) SINK(acc[mf][nf]);
    }
#undef STAGE
#undef RB
#undef RA
#undef G
#undef TILE
}

// ---------------------------------------------------------------------------
// Fallback GEMM (static 64 KiB LDS) if dynamic-LDS attr fails
// ---------------------------------------------------------------------------
__global__ void gemm_bf_kernel(const unsigned short* __restrict__ Xb,
                               const unsigned short* __restrict__ Wt,
                               const float* __restrict__ bias,
                               float* __restrict__ out) {
    __shared__ __align__(16) unsigned short As[128][32];
    __shared__ __align__(16) unsigned short Bs[128][32];

    const int tid  = threadIdx.x;
    const int lane = tid & 63;
    const int wid  = tid >> 6;
    const int wr   = wid >> 1;
    const int wc   = wid & 1;
    const int bn   = blockIdx.x;
    const int bm   = blockIdx.y;

    f32x4 acc[4][4];
#pragma unroll
    for (int i = 0; i < 4; ++i)
#pragma unroll
        for (int j = 0; j < 4; ++j) {
            f32x4 z = {0.f, 0.f, 0.f, 0.f};
            acc[i][j] = z;
        }

    const unsigned short* abase =
        Xb + (size_t)(bm * 128 + wid * 16 + (lane >> 2)) * KDIM + (lane & 3) * 8;
    const unsigned short* bbase =
        Wt + (size_t)(bn * 128 + wid * 16 + (lane >> 2)) * KDIM + (lane & 3) * 8;

    for (int kt = 0; kt < KDIM; kt += 32) {
#pragma unroll
        for (int j = 0; j < 2; ++j)
            __builtin_amdgcn_global_load_lds(
                (const __attribute__((address_space(1))) unsigned int*)(abase + (size_t)j * 64 * KDIM + kt),
                (__attribute__((address_space(3))) unsigned int*)(&As[j * 64 + wid * 16][0]),
                16, 0, 0);
#pragma unroll
        for (int j = 0; j < 2; ++j)
            __builtin_amdgcn_global_load_lds(
                (const __attribute__((address_space(1))) unsigned int*)(bbase + (size_t)j * 64 * KDIM + kt),
                (__attribute__((address_space(3))) unsigned int*)(&Bs[j * 64 + wid * 16][0]),
                16, 0, 0);
        __syncthreads();

        short8 af[4], bfr[4];
#pragma unroll
        for (int mi = 0; mi < 4; ++mi)
            af[mi] = *(const short8*)&As[wr * 64 + mi * 16 + (lane & 15)][(lane >> 4) * 8];
#pragma unroll
        for (int ni = 0; ni < 4; ++ni)
            bfr[ni] = *(const short8*)&Bs[wc * 64 + ni * 16 + (lane & 15)][(lane >> 4) * 8];

#pragma unroll
        for (int mi = 0; mi < 4; ++mi)
#pragma unroll
            for (int ni = 0; ni < 4; ++ni)
                acc[mi][ni] = MFMA16(af[mi], bfr[ni], acc[mi][ni]);

        __syncthreads();
    }

#pragma unroll
    for (int ni = 0; ni < 4; ++ni) {
        const int col = bn * 128 + wc * 64 + ni * 16 + (lane & 15);
        if (col < NDIM) {
            const float bv = bias[col];
#pragma unroll
            for (int mi = 0; mi < 4; ++mi) {
                const int row = bm * 128 + wr * 64 + mi * 16 + ((lane >> 4) << 2);
                float* op = out + (size_t)row * NDIM + col;
#pragma unroll
                for (int r = 0; r < 4; ++r)
                    op[(size_t)r * NDIM] = acc[mi][ni][r] + bv;
            }
        }
    }
}

// ---------------------------------------------------------------------------
// Kernel 3: activation. One wave per (row, span of 51 cols).
// ---------------------------------------------------------------------------
__global__ void act_kernel(const float* __restrict__ outp,
                           const float* __restrict__ u,
                           float* __restrict__ dt) {
    const int lane  = threadIdx.x & 63;
    const int gwave = (blockIdx.x * 256 + threadIdx.x) >> 6;
    const int nwave = gridDim.x * 4;
    const int total = MDIM * 20;
    const float NEG_INF = -__builtin_inff();

    for (int unit = gwave; unit < total; unit += nwave) {
        const int row = unit / 20;
        const int sp  = unit - row * 20;
        const size_t base = (size_t)row * NDIM + sp * 51;

        float o = 0.f, uu = 0.5f;
        if (lane < 51) {
            o  = outp[base + lane];
            uu = u[base + lane];
        }
        const bool soft = (lane >= 1) && (lane < 51);

        const float uc = fmaxf(uu, 1e-9f);
        const float g  = -__logf(-__logf(uc));
        float z = soft ? (o + g) * 5.0f : NEG_INF;

        float m = z;
#pragma unroll
        for (int off = 32; off; off >>= 1) m = fmaxf(m, __shfl_xor(m, off));
        float e = soft ? __expf(z - m) : 0.f;
        float s = e;
#pragma unroll
        for (int off = 32; off; off >>= 1) s += __shfl_xor(s, off);

        float res;
        if (lane == 0) {
            const float ex = __expf(-2.0f * fabsf(o));
            const float t  = (1.0f - ex) / (1.0f + ex);
            res = copysignf(t, o);
        } else {
            res = e / s;
        }
        if (lane < 51) dt[base + lane] = res;
    }
}

// ---------------------------------------------------------------------------
extern "C" void kernel_launch(void* const* d_in, const int* in_sizes, int n_in,
                              void* d_out, int out_size, void* d_ws, size_t ws_size,
                              hipStream_t stream) {
    const float* x = (const float*)d_in[0];
    const float* W = (const float*)d_in[1];
    const float* b = (const float*)d_in[2];
    const float* u = (const float*)d_in[3];
    float* out = (float*)d_out;                      // outputs [M][N]
    float* dt  = out + (size_t)MDIM * NDIM;          // data_t  [M][N]
    unsigned short* Wt = (unsigned short*)d_ws;      // bf16 [NPAD][K], 4 MiB
    unsigned short* Xb = Wt + (size_t)NPAD * KDIM;   // bf16 [M][K], 64 MiB

    prep_w_kernel<<<512, 256, 0, stream>>>(W, Wt);
    prep_x_kernel<<<2048, 256, 0, stream>>>(x, Xb);

    auto* real_fn = gemm_abl<0, 1>;
    auto* abl_fn  = gemm_abl<1, 3>;
    const hipError_t ok0 = hipFuncSetAttribute(
        (const void*)real_fn, hipFuncAttributeMaxDynamicSharedMemorySize, 131072);
    const hipError_t ok1 = hipFuncSetAttribute(
        (const void*)abl_fn, hipFuncAttributeMaxDynamicSharedMemorySize, 131072);

    if (ok0 == hipSuccess && ok1 == hipSuccess) {
        // Ablation probe (noMFMA, 3x K-length): writes nothing; its rocprof
        // duration is the memory/sync skeleton's standalone cost.
        abl_fn<<<256, 512, 131072, stream>>>(Xb, Wt, b, out);
        // Real GEMM (R6-identical schedule).
        real_fn<<<256, 512, 131072, stream>>>(Xb, Wt, b, out);
    } else {
        gemm_bf_kernel<<<dim3(8, 128), 256, 0, stream>>>(Xb, Wt, b, out);
    }

    act_kernel<<<8192, 256, 0, stream>>>(out, u, dt);
}

// Round 8
// 228.192 us; speedup vs baseline: 1.2032x; 1.2032x over previous
//
#include <hip/hip_runtime.h>
#include <stdint.h>

#define MDIM 16384
#define NDIM 1020
#define KDIM 2048
#define NPAD 1024
#define TK   (KDIM / 64)   // 32 K-tiles of BK=64

typedef __attribute__((ext_vector_type(4))) float f32x4;
typedef __attribute__((ext_vector_type(8))) short short8;

#define MFMA16(a, b, c) __builtin_amdgcn_mfma_f32_16x16x32_bf16((a), (b), (c), 0, 0, 0)

// asm ds_read_b128, register-only constraints; completion via counted lgkmcnt.
template <int OFF>
static __device__ __forceinline__ short8 dsr(unsigned addr) {
    short8 r;
    asm volatile("ds_read_b128 %0, %1 offset:%2" : "=v"(r) : "v"(addr), "i"(OFF));
    return r;
}

// rule 18: wait + scheduling fence so MFMAs can't hoist above the wait.
#define LGKM(N)                                                       \
    asm volatile("s_waitcnt lgkmcnt(" #N ")" ::: "memory");           \
    __builtin_amdgcn_sched_barrier(0);

// f32 -> bf16 round-to-nearest-even
__device__ __forceinline__ unsigned short f2bf(float f) {
    unsigned int u = __float_as_uint(f);
    unsigned int r = (u + 0x7FFFu + ((u >> 16) & 1u)) >> 16;
    return (unsigned short)r;
}

// ---------------------------------------------------------------------------
// Kernel 1: W [K=2048][N=1020] f32 -> Wt [NPAD=1024][K=2048] bf16 (transposed)
// ---------------------------------------------------------------------------
__global__ void prep_w_kernel(const float* __restrict__ W,
                              unsigned short* __restrict__ Wt) {
    const int id = blockIdx.x * 256 + threadIdx.x;  // 512 blocks * 256
    const int n0 = (id & 255) * 4;
    const int k0 = (id >> 8) * 4;
    float a[4][4];
    if (n0 < NDIM) {
#pragma unroll
        for (int i = 0; i < 4; ++i) {
            const float* p = W + (size_t)(k0 + i) * NDIM + n0;
            a[i][0] = p[0]; a[i][1] = p[1]; a[i][2] = p[2]; a[i][3] = p[3];
        }
    } else {
#pragma unroll
        for (int i = 0; i < 4; ++i)
#pragma unroll
            for (int j = 0; j < 4; ++j) a[i][j] = 0.f;
    }
#pragma unroll
    for (int j = 0; j < 4; ++j) {
        uint2 p;
        p.x = (unsigned)f2bf(a[0][j]) | ((unsigned)f2bf(a[1][j]) << 16);
        p.y = (unsigned)f2bf(a[2][j]) | ((unsigned)f2bf(a[3][j]) << 16);
        *(uint2*)(Wt + (size_t)(n0 + j) * KDIM + k0) = p;
    }
}

// ---------------------------------------------------------------------------
// Kernel 1b: x [M][K] f32 -> Xb [M][K] bf16
// ---------------------------------------------------------------------------
__global__ void prep_x_kernel(const float* __restrict__ x,
                              unsigned short* __restrict__ Xb) {
    const size_t total = (size_t)MDIM * KDIM;
    const size_t stride = (size_t)gridDim.x * 256 * 8;
    for (size_t i = ((size_t)blockIdx.x * 256 + threadIdx.x) * 8; i < total; i += stride) {
        const float4 v0 = *(const float4*)(x + i);
        const float4 v1 = *(const float4*)(x + i + 4);
        uint4 p;
        p.x = (unsigned)f2bf(v0.x) | ((unsigned)f2bf(v0.y) << 16);
        p.y = (unsigned)f2bf(v0.z) | ((unsigned)f2bf(v0.w) << 16);
        p.z = (unsigned)f2bf(v1.x) | ((unsigned)f2bf(v1.y) << 16);
        p.w = (unsigned)f2bf(v1.z) | ((unsigned)f2bf(v1.w) << 16);
        *(uint4*)(Xb + i) = p;
    }
}

// ---------------------------------------------------------------------------
// Kernel 2 (R8): 256x256 GEMM, BK=64, 512 thr / 8 waves (2 wr x 4 wc).
// A: LDS (A-only, 2 x 32 KiB, DMA-staged, XOR-swizzled — verified R3/R4 path).
// B: DIRECT global->register loads (16 B/lane contiguous in Wt), register
//    double-buffered one tile ahead (bP/bQ) — B never touches LDS.
// Per tile: 4 DMA STAGEs (A t+1) + 8 B-loads (t+1) issued first; then 16
// ds_read_b128 (A t) stream under 16 MFMA quads gated by counted lgkmcnt;
// ONE vmcnt(0) + ONE s_barrier at tile end (all vm ops are ~2400 cyc old by
// then -> near-zero wait). LDS reads/tile/CU drop 192->128.
// ---------------------------------------------------------------------------
extern "C" __global__ __launch_bounds__(512, 2) void gemm9_kernel(
    const unsigned short* __restrict__ Xb,
    const unsigned short* __restrict__ Wt,
    const float* __restrict__ bias,
    float* __restrict__ out) {
    extern __shared__ unsigned short lds_raw[];  // 2 bufs x (A 256x64) = 64 KiB

    const int tid  = threadIdx.x;
    const int lane = tid & 63;
    const int wid  = tid >> 6;   // 0..7
    const int wr   = wid >> 2;   // 0..1 (M)
    const int wc   = wid & 3;    // 0..3 (N)

    // XCD-aware swizzle: 256 blocks, 8 XCDs, 32 consecutive per XCD
    const int bid = blockIdx.x;
    const int swz = (bid & 7) * 32 + (bid >> 3);
    const int bm  = swz >> 2;    // 0..63
    const int bn  = swz & 3;     // 0..3

    // A staging source (rule 21 pre-swizzle; verified R3/R4)
    const int srow = wid * 8 + (lane >> 3);
    const int scb  = ((lane & 7) ^ (lane >> 3)) * 8;
    const unsigned short* aS = Xb + (size_t)(bm * 256 + srow) * KDIM + scb;

#define STAGEA(BUFI, STRIPE, S) do {                                             \
    const unsigned short* sp_ =                                                  \
        aS + (size_t)((STRIPE) * 64) * KDIM + (size_t)(((S) & 31) * 64);         \
    __builtin_amdgcn_global_load_lds(                                            \
        (const __attribute__((address_space(1))) unsigned int*)sp_,              \
        (__attribute__((address_space(3))) unsigned int*)(lds_raw +              \
            (BUFI) * 16384 + ((STRIPE) * 64 + wid * 8) * 64),                    \
        16, 0, 0);                                                               \
} while (0)

    // A LDS read addressing (verified): byte = buf*32768 + (wr*128+mf*16+l15)*128
    //                                          + (((k2*4+hi)^l7)<<4)
    const unsigned ldsbase =
        (unsigned)(uintptr_t)(__attribute__((address_space(3))) unsigned short*)lds_raw;
    const unsigned l15 = lane & 15, hi = lane >> 4, l7 = lane & 7;
    const unsigned c0 = (unsigned)((0 * 4 + hi) ^ l7) << 4;
    const unsigned c1 = (unsigned)((1 * 4 + hi) ^ l7) << 4;
    const unsigned pbA = ldsbase + (unsigned)(wr * 128 + l15) * 128;
    const unsigned aA0_0 = pbA + c0,          aA0_1 = pbA + c1;
    const unsigned aA1_0 = pbA + 32768u + c0, aA1_1 = pbA + 32768u + c1;

    // B direct-load base: frag(nf,k2) @tile T = bsrc + nf*16*KDIM + (T&31)*64 + k2*32
    const unsigned short* bsrc =
        Wt + (size_t)(bn * 256 + wc * 64 + l15) * KDIM + hi * 8;

#define LOADB(DST, T) {                                                   \
    const unsigned short* bp_ = bsrc + (size_t)(((T) & 31)) * 64;         \
    DST[0][0] = *(const short8*)(bp_);                                    \
    DST[0][1] = *(const short8*)(bp_ + 32);                               \
    DST[1][0] = *(const short8*)(bp_ + 16 * KDIM);                        \
    DST[1][1] = *(const short8*)(bp_ + 16 * KDIM + 32);                   \
    DST[2][0] = *(const short8*)(bp_ + 32 * KDIM);                        \
    DST[2][1] = *(const short8*)(bp_ + 32 * KDIM + 32);                   \
    DST[3][0] = *(const short8*)(bp_ + 48 * KDIM);                        \
    DST[3][1] = *(const short8*)(bp_ + 48 * KDIM + 32);                   \
}

    f32x4 acc[8][4];
#pragma unroll
    for (int i = 0; i < 8; ++i)
#pragma unroll
        for (int j = 0; j < 4; ++j) {
            f32x4 z = {0.f, 0.f, 0.f, 0.f};
            acc[i][j] = z;
        }

    short8 bP[4][2], bQ[4][2];   // B register double-buffer [nf][k2]

#define G4(MF, AF, KH, BC, LG)                                        \
    LGKM(LG)                                                          \
    acc[MF][0] = MFMA16(AF, BC[0][KH], acc[MF][0]);                   \
    acc[MF][1] = MFMA16(AF, BC[1][KH], acc[MF][1]);                   \
    acc[MF][2] = MFMA16(AF, BC[2][KH], acc[MF][2]);                   \
    acc[MF][3] = MFMA16(AF, BC[3][KH], acc[MF][3]);

// lgkm counts: after x0-x7 issued (8 out): G(mf0)->7 .. G(mf3)->4. y0-3 issued
// (<=8 out): G(mf4) needs x4, ops after = x5-7,y0-3 -> 7 .. G(mf7)->4. y4-7
// issued: G(k1,mf0) needs y0, after = y1-7 -> 7 .. G(k1,mf3)->4; G(k1,mf4)
// needs y4 -> 3,2,1,0. Max 8 A-frags live (32 VGPR).
#define TILE(T, BUF, NB, BCUR, BNXT)                                            \
  {                                                                             \
    STAGEA(NB, 0, (T) + 1); STAGEA(NB, 1, (T) + 1);                             \
    STAGEA(NB, 2, (T) + 1); STAGEA(NB, 3, (T) + 1);                             \
    LOADB(BNXT, (T) + 1)                                                        \
    __builtin_amdgcn_sched_barrier(0);                                          \
    __builtin_amdgcn_s_setprio(1);                                              \
    short8 x0 = dsr<0>(aA##BUF##_0),     x1 = dsr<2048>(aA##BUF##_0);           \
    short8 x2 = dsr<4096>(aA##BUF##_0),  x3 = dsr<6144>(aA##BUF##_0);           \
    short8 x4 = dsr<8192>(aA##BUF##_0),  x5 = dsr<10240>(aA##BUF##_0);          \
    short8 x6 = dsr<12288>(aA##BUF##_0), x7 = dsr<14336>(aA##BUF##_0);          \
    G4(0, x0, 0, BCUR, 7) G4(1, x1, 0, BCUR, 6)                                 \
    G4(2, x2, 0, BCUR, 5) G4(3, x3, 0, BCUR, 4)                                 \
    short8 y0 = dsr<0>(aA##BUF##_1),     y1 = dsr<2048>(aA##BUF##_1);           \
    short8 y2 = dsr<4096>(aA##BUF##_1),  y3 = dsr<6144>(aA##BUF##_1);           \
    G4(4, x4, 0, BCUR, 7) G4(5, x5, 0, BCUR, 6)                                 \
    G4(6, x6, 0, BCUR, 5) G4(7, x7, 0, BCUR, 4)                                 \
    short8 y4 = dsr<8192>(aA##BUF##_1),  y5 = dsr<10240>(aA##BUF##_1);          \
    short8 y6 = dsr<12288>(aA##BUF##_1), y7 = dsr<14336>(aA##BUF##_1);          \
    G4(0, y0, 1, BCUR, 7) G4(1, y1, 1, BCUR, 6)                                 \
    G4(2, y2, 1, BCUR, 5) G4(3, y3, 1, BCUR, 4)                                 \
    G4(4, y4, 1, BCUR, 3) G4(5, y5, 1, BCUR, 2)                                 \
    G4(6, y6, 1, BCUR, 1) G4(7, y7, 1, BCUR, 0)                                 \
    __builtin_amdgcn_s_setprio(0);                                              \
    asm volatile("s_waitcnt vmcnt(0)" ::: "memory");                            \
    __builtin_amdgcn_sched_barrier(0);                                          \
    __builtin_amdgcn_s_barrier();                                               \
  }

    // ---- prologue: A(0) -> buf0, B(0) -> bP ----
    STAGEA(0, 0, 0); STAGEA(0, 1, 0); STAGEA(0, 2, 0); STAGEA(0, 3, 0);
    LOADB(bP, 0)
    asm volatile("s_waitcnt vmcnt(0)" ::: "memory");
    __builtin_amdgcn_sched_barrier(0);
    __builtin_amdgcn_s_barrier();

    for (int t2 = 0; t2 < TK; t2 += 2) {
        TILE(t2,     0, 1, bP, bQ)
        TILE(t2 + 1, 1, 0, bQ, bP)
    }

    // ---- epilogue: bias + store (C/D: col=lane&15, row=(lane>>4)*4+r) ----
#pragma unroll
    for (int nf = 0; nf < 4; ++nf) {
        const int col = bn * 256 + wc * 64 + nf * 16 + (lane & 15);
        if (col < NDIM) {
            const float bv = bias[col];
#pragma unroll
            for (int mf = 0; mf < 8; ++mf) {
                const int row = bm * 256 + wr * 128 + mf * 16 + ((lane >> 4) << 2);
                float* op = out + (size_t)row * NDIM + col;
#pragma unroll
                for (int r = 0; r < 4; ++r)
                    op[(size_t)r * NDIM] = acc[mf][nf][r] + bv;
            }
        }
    }
#undef STAGEA
#undef LOADB
#undef G4
#undef TILE
}

// ---------------------------------------------------------------------------
// Fallback GEMM (static 64 KiB LDS) if dynamic-LDS attr fails
// ---------------------------------------------------------------------------
__global__ void gemm_bf_kernel(const unsigned short* __restrict__ Xb,
                               const unsigned short* __restrict__ Wt,
                               const float* __restrict__ bias,
                               float* __restrict__ out) {
    __shared__ __align__(16) unsigned short As[128][32];
    __shared__ __align__(16) unsigned short Bs[128][32];

    const int tid  = threadIdx.x;
    const int lane = tid & 63;
    const int wid  = tid >> 6;
    const int wr   = wid >> 1;
    const int wc   = wid & 1;
    const int bn   = blockIdx.x;
    const int bm   = blockIdx.y;

    f32x4 acc[4][4];
#pragma unroll
    for (int i = 0; i < 4; ++i)
#pragma unroll
        for (int j = 0; j < 4; ++j) {
            f32x4 z = {0.f, 0.f, 0.f, 0.f};
            acc[i][j] = z;
        }

    const unsigned short* abase =
        Xb + (size_t)(bm * 128 + wid * 16 + (lane >> 2)) * KDIM + (lane & 3) * 8;
    const unsigned short* bbase =
        Wt + (size_t)(bn * 128 + wid * 16 + (lane >> 2)) * KDIM + (lane & 3) * 8;

    for (int kt = 0; kt < KDIM; kt += 32) {
#pragma unroll
        for (int j = 0; j < 2; ++j)
            __builtin_amdgcn_global_load_lds(
                (const __attribute__((address_space(1))) unsigned int*)(abase + (size_t)j * 64 * KDIM + kt),
                (__attribute__((address_space(3))) unsigned int*)(&As[j * 64 + wid * 16][0]),
                16, 0, 0);
#pragma unroll
        for (int j = 0; j < 2; ++j)
            __builtin_amdgcn_global_load_lds(
                (const __attribute__((address_space(1))) unsigned int*)(bbase + (size_t)j * 64 * KDIM + kt),
                (__attribute__((address_space(3))) unsigned int*)(&Bs[j * 64 + wid * 16][0]),
                16, 0, 0);
        __syncthreads();

        short8 af[4], bfr[4];
#pragma unroll
        for (int mi = 0; mi < 4; ++mi)
            af[mi] = *(const short8*)&As[wr * 64 + mi * 16 + (lane & 15)][(lane >> 4) * 8];
#pragma unroll
        for (int ni = 0; ni < 4; ++ni)
            bfr[ni] = *(const short8*)&Bs[wc * 64 + ni * 16 + (lane & 15)][(lane >> 4) * 8];

#pragma unroll
        for (int mi = 0; mi < 4; ++mi)
#pragma unroll
            for (int ni = 0; ni < 4; ++ni)
                acc[mi][ni] = MFMA16(af[mi], bfr[ni], acc[mi][ni]);

        __syncthreads();
    }

#pragma unroll
    for (int ni = 0; ni < 4; ++ni) {
        const int col = bn * 128 + wc * 64 + ni * 16 + (lane & 15);
        if (col < NDIM) {
            const float bv = bias[col];
#pragma unroll
            for (int mi = 0; mi < 4; ++mi) {
                const int row = bm * 128 + wr * 64 + mi * 16 + ((lane >> 4) << 2);
                float* op = out + (size_t)row * NDIM + col;
#pragma unroll
                for (int r = 0; r < 4; ++r)
                    op[(size_t)r * NDIM] = acc[mi][ni][r] + bv;
            }
        }
    }
}

// ---------------------------------------------------------------------------
// Kernel 3: activation. One wave per (row, span of 51 cols).
// ---------------------------------------------------------------------------
__global__ void act_kernel(const float* __restrict__ outp,
                           const float* __restrict__ u,
                           float* __restrict__ dt) {
    const int lane  = threadIdx.x & 63;
    const int gwave = (blockIdx.x * 256 + threadIdx.x) >> 6;
    const int nwave = gridDim.x * 4;
    const int total = MDIM * 20;
    const float NEG_INF = -__builtin_inff();

    for (int unit = gwave; unit < total; unit += nwave) {
        const int row = unit / 20;
        const int sp  = unit - row * 20;
        const size_t base = (size_t)row * NDIM + sp * 51;

        float o = 0.f, uu = 0.5f;
        if (lane < 51) {
            o  = outp[base + lane];
            uu = u[base + lane];
        }
        const bool soft = (lane >= 1) && (lane < 51);

        const float uc = fmaxf(uu, 1e-9f);
        const float g  = -__logf(-__logf(uc));
        float z = soft ? (o + g) * 5.0f : NEG_INF;

        float m = z;
#pragma unroll
        for (int off = 32; off; off >>= 1) m = fmaxf(m, __shfl_xor(m, off));
        float e = soft ? __expf(z - m) : 0.f;
        float s = e;
#pragma unroll
        for (int off = 32; off; off >>= 1) s += __shfl_xor(s, off);

        float res;
        if (lane == 0) {
            const float ex = __expf(-2.0f * fabsf(o));
            const float t  = (1.0f - ex) / (1.0f + ex);
            res = copysignf(t, o);
        } else {
            res = e / s;
        }
        if (lane < 51) dt[base + lane] = res;
    }
}

// ---------------------------------------------------------------------------
extern "C" void kernel_launch(void* const* d_in, const int* in_sizes, int n_in,
                              void* d_out, int out_size, void* d_ws, size_t ws_size,
                              hipStream_t stream) {
    const float* x = (const float*)d_in[0];
    const float* W = (const float*)d_in[1];
    const float* b = (const float*)d_in[2];
    const float* u = (const float*)d_in[3];
    float* out = (float*)d_out;                      // outputs [M][N]
    float* dt  = out + (size_t)MDIM * NDIM;          // data_t  [M][N]
    unsigned short* Wt = (unsigned short*)d_ws;      // bf16 [NPAD][K], 4 MiB
    unsigned short* Xb = Wt + (size_t)NPAD * KDIM;   // bf16 [M][K], 64 MiB

    prep_w_kernel<<<512, 256, 0, stream>>>(W, Wt);
    prep_x_kernel<<<2048, 256, 0, stream>>>(x, Xb);

    const hipError_t attr_ok = hipFuncSetAttribute(
        (const void*)gemm9_kernel, hipFuncAttributeMaxDynamicSharedMemorySize, 65536);
    if (attr_ok == hipSuccess) {
        gemm9_kernel<<<256, 512, 65536, stream>>>(Xb, Wt, b, out);
    } else {
        gemm_bf_kernel<<<dim3(8, 128), 256, 0, stream>>>(Xb, Wt, b, out);
    }

    act_kernel<<<8192, 256, 0, stream>>>(out, u, dt);
}

// Round 10
// 182.913 us; speedup vs baseline: 1.5010x; 1.2475x over previous
//
#include <hip/hip_runtime.h>
#include <stdint.h>

#define MDIM 16384
#define NDIM 1020
#define KDIM 2048
#define NPAD 1024
#define TK   (KDIM / 64)   // 32 K-tiles of BK=64

typedef __attribute__((ext_vector_type(4))) float f32x4;
typedef __attribute__((ext_vector_type(8))) short short8;

#define MFMA16(a, b, c) __builtin_amdgcn_mfma_f32_16x16x32_bf16((a), (b), (c), 0, 0, 0)

// asm ds_read_b128 / ds_write_b64, register-only constraints; completion via
// manual lgkmcnt (+ sched_barrier(0) per rule 18).
template <int OFF>
static __device__ __forceinline__ short8 dsr(unsigned addr) {
    short8 r;
    asm volatile("ds_read_b128 %0, %1 offset:%2" : "=v"(r) : "v"(addr), "i"(OFF));
    return r;
}
template <int OFF>
static __device__ __forceinline__ void dsw64(unsigned addr, uint2 v) {
    asm volatile("ds_write_b64 %0, %1 offset:%2" :: "v"(addr), "v"(v), "i"(OFF));
}

// f32 -> bf16 round-to-nearest (half-up) + pack two into one u32:
// r = bits + 0x8000; pack = v_perm([r1.b3 r1.b2 r0.b3 r0.b2])
__device__ __forceinline__ unsigned packbf(float lo, float hi) {
    const unsigned r0 = __float_as_uint(lo) + 0x8000u;
    const unsigned r1 = __float_as_uint(hi) + 0x8000u;
    return __builtin_amdgcn_perm(r1, r0, 0x07060302u);
}

// f32 -> bf16 RNE (prep kernels)
__device__ __forceinline__ unsigned short f2bf(float f) {
    unsigned int u = __float_as_uint(f);
    unsigned int r = (u + 0x7FFFu + ((u >> 16) & 1u)) >> 16;
    return (unsigned short)r;
}

// ---------------------------------------------------------------------------
// Kernel 1: W [K=2048][N=1020] f32 -> Wt [NPAD=1024][K=2048] bf16 (transposed)
// ---------------------------------------------------------------------------
__global__ void prep_w_kernel(const float* __restrict__ W,
                              unsigned short* __restrict__ Wt) {
    const int id = blockIdx.x * 256 + threadIdx.x;  // 512 blocks * 256
    const int n0 = (id & 255) * 4;
    const int k0 = (id >> 8) * 4;
    float a[4][4];
    if (n0 < NDIM) {
#pragma unroll
        for (int i = 0; i < 4; ++i) {
            const float* p = W + (size_t)(k0 + i) * NDIM + n0;
            a[i][0] = p[0]; a[i][1] = p[1]; a[i][2] = p[2]; a[i][3] = p[3];
        }
    } else {
#pragma unroll
        for (int i = 0; i < 4; ++i)
#pragma unroll
            for (int j = 0; j < 4; ++j) a[i][j] = 0.f;
    }
#pragma unroll
    for (int j = 0; j < 4; ++j) {
        uint2 p;
        p.x = (unsigned)f2bf(a[0][j]) | ((unsigned)f2bf(a[1][j]) << 16);
        p.y = (unsigned)f2bf(a[2][j]) | ((unsigned)f2bf(a[3][j]) << 16);
        *(uint2*)(Wt + (size_t)(n0 + j) * KDIM + k0) = p;
    }
}

// ---------------------------------------------------------------------------
// Kernel 1b (FALLBACK PATH ONLY): x f32 -> Xb bf16
// ---------------------------------------------------------------------------
__global__ void prep_x_kernel(const float* __restrict__ x,
                              unsigned short* __restrict__ Xb) {
    const size_t total = (size_t)MDIM * KDIM;
    const size_t stride = (size_t)gridDim.x * 256 * 8;
    for (size_t i = ((size_t)blockIdx.x * 256 + threadIdx.x) * 8; i < total; i += stride) {
        const float4 v0 = *(const float4*)(x + i);
        const float4 v1 = *(const float4*)(x + i + 4);
        uint4 p;
        p.x = (unsigned)f2bf(v0.x) | ((unsigned)f2bf(v0.y) << 16);
        p.y = (unsigned)f2bf(v0.z) | ((unsigned)f2bf(v0.w) << 16);
        p.z = (unsigned)f2bf(v1.x) | ((unsigned)f2bf(v1.y) << 16);
        p.w = (unsigned)f2bf(v1.z) | ((unsigned)f2bf(v1.w) << 16);
        *(uint4*)(Xb + i) = p;
    }
}

// ---------------------------------------------------------------------------
// Kernel 2 (R10 = R9 + swizzle-carry fix): 256x256 GEMM, BK=64, 8 waves.
// A is staged DIRECTLY from f32 x (reg-load float4 -> packbf -> swizzled
// ds_write_b64); no prep_x pass. Schedule = R3/R4 (98.4us verified).
// WRITE SWIZZLE FIX: block index must be XOR'd with r&7 = 4*(i&1)+h. The
// 4*(i&1) part is bit 6 of the byte address and MUST be XOR (R9 added it as
// an immediate -> carry into row bit 7 when ((g>>1)^h)>=4 -> corrupt LDS).
// Two bases: awbE (even i), awbO = awbE ^ 0x40 (odd i); imm offset = i*512
// (row stride only; h*128 + i*512 <= 3968 < 4096 -> carry-free).
// ---------------------------------------------------------------------------
extern "C" __global__ __launch_bounds__(512, 2) void gemm10_kernel(
    const float* __restrict__ x,
    const unsigned short* __restrict__ Wt,
    const float* __restrict__ bias,
    float* __restrict__ out) {
    extern __shared__ unsigned short lds_raw[];  // 2 bufs x (A 32KB + B 32KB)

    const int tid  = threadIdx.x;
    const int lane = tid & 63;
    const int wid  = tid >> 6;   // 0..7
    const int wr   = wid >> 2;   // 0..1 (M)
    const int wc   = wid & 3;    // 0..3 (N)

    // XCD-aware swizzle: 256 blocks, 8 XCDs, 32 consecutive per XCD.
    const int bid = blockIdx.x;
    const int swz = (bid & 7) * 32 + (bid >> 3);
    const int bm  = swz >> 2;    // 0..63
    const int bn  = swz & 3;     // 0..3

    // B staging source (rule 21 pre-swizzle; verified R3/R4)
    const int srow = wid * 8 + (lane >> 3);
    const int scb  = ((lane & 7) ^ (lane >> 3)) * 8;
    const unsigned short* bS = Wt + (size_t)(bn * 256 + srow) * KDIM + scb;

#define STAGEB(BUFI, STRIPE, S) do {                                             \
    const unsigned short* sp_ =                                                  \
        bS + (size_t)((STRIPE) * 64) * KDIM + (size_t)(((S) & 31) * 64);         \
    __builtin_amdgcn_global_load_lds(                                            \
        (const __attribute__((address_space(1))) unsigned int*)sp_,              \
        (__attribute__((address_space(3))) unsigned int*)(lds_raw +              \
            (BUFI) * 32768 + 16384 + ((STRIPE) * 64 + wid * 8) * 64),            \
        16, 0, 0);                                                               \
} while (0)

    // A direct-f32 source: lane covers row r = wid*32 + i*4 + h (i=0..7),
    // k-group g = lane&15 (float4 at k=g*4) -- fully coalesced.
    const int h = lane >> 4, g = lane & 15;
    const float* aF = x + (size_t)(bm * 256 + wid * 32 + h) * KDIM + g * 4;

    // A LDS write: byte = buf*65536 + r*128 + ((g>>1 ^ (r&7))<<4) + (g&1)*8
    // r&7 = 4*(i&1)+h  ->  base(E: i even) has ((g>>1)^h)<<4; O = E ^ 0x40.
    const unsigned ldsbase =
        (unsigned)(uintptr_t)(__attribute__((address_space(3))) unsigned short*)lds_raw;
    const unsigned awbE =
        ldsbase + (unsigned)(wid * 32 + h) * 128 +
        ((unsigned)((g >> 1) ^ h) << 4) + (unsigned)(g & 1) * 8;
    const unsigned awbO  = awbE ^ 0x40u;
    const unsigned awb0E = awbE,           awb0O = awbO;
    const unsigned awb1E = awbE + 65536u,  awb1O = awbO + 65536u;

    float4 av[8];
#define AGLD(T) {                                                     \
    const float* ap_ = aF + (size_t)(((T) & 31) * 64);                \
    av[0] = *(const float4*)(ap_);                                    \
    av[1] = *(const float4*)(ap_ + 4 * KDIM);                         \
    av[2] = *(const float4*)(ap_ + 8 * KDIM);                         \
    av[3] = *(const float4*)(ap_ + 12 * KDIM);                        \
    av[4] = *(const float4*)(ap_ + 16 * KDIM);                        \
    av[5] = *(const float4*)(ap_ + 20 * KDIM);                        \
    av[6] = *(const float4*)(ap_ + 24 * KDIM);                        \
    av[7] = *(const float4*)(ap_ + 28 * KDIM);                        \
}
#define CVT1(AWE, AWO, I)                                             \
    { uint2 v_;                                                       \
      v_.x = packbf(av[I].x, av[I].y);                                \
      v_.y = packbf(av[I].z, av[I].w);                                \
      dsw64<(I) * 512>(((I) & 1) ? (AWO) : (AWE), v_); }
#define CVTW(AWE, AWO)                                                \
    CVT1(AWE, AWO, 0) CVT1(AWE, AWO, 1) CVT1(AWE, AWO, 2)             \
    CVT1(AWE, AWO, 3) CVT1(AWE, AWO, 4) CVT1(AWE, AWO, 5)             \
    CVT1(AWE, AWO, 6) CVT1(AWE, AWO, 7)

    // A/B LDS read addressing (verified R3/R4)
    const unsigned l15 = lane & 15, hi = lane >> 4, l7 = lane & 7;
    const unsigned c0 = (unsigned)((0 * 4 + hi) ^ l7) << 4;
    const unsigned c1 = (unsigned)((1 * 4 + hi) ^ l7) << 4;
    const unsigned pbA = ldsbase + (unsigned)(wr * 128 + l15) * 128;
    const unsigned pbB = ldsbase + 32768u + (unsigned)(wc * 64 + l15) * 128;
    const unsigned aA0_0 = pbA + c0,          aA0_1 = pbA + c1;
    const unsigned aA1_0 = pbA + 65536u + c0, aA1_1 = pbA + 65536u + c1;
    const unsigned bB0_0 = pbB + c0,          bB0_1 = pbB + c1;
    const unsigned bB1_0 = pbB + 65536u + c0, bB1_1 = pbB + 65536u + c1;

    f32x4 acc[8][4];
#pragma unroll
    for (int i = 0; i < 8; ++i)
#pragma unroll
        for (int j = 0; j < 4; ++j) {
            f32x4 z = {0.f, 0.f, 0.f, 0.f};
            acc[i][j] = z;
        }

#define PH_TAIL                                                       \
    __builtin_amdgcn_s_barrier();                                     \
    asm volatile("s_waitcnt lgkmcnt(0)" ::: "memory");                \
    __builtin_amdgcn_sched_barrier(0);                                \
    __builtin_amdgcn_s_setprio(1);

#define PH_MFMA(MF0)                                                  \
    _Pragma("unroll")                                                 \
    for (int nf = 0; nf < 4; ++nf) {                                  \
        acc[MF0][nf]     = MFMA16(af0[0], bfv[nf][0], acc[MF0][nf]);      \
        acc[MF0][nf]     = MFMA16(af0[1], bfv[nf][1], acc[MF0][nf]);      \
        acc[MF0 + 1][nf] = MFMA16(af1[0], bfv[nf][0], acc[MF0 + 1][nf]);  \
        acc[MF0 + 1][nf] = MFMA16(af1[1], bfv[nf][1], acc[MF0 + 1][nf]);  \
    }                                                                 \
    __builtin_amdgcn_sched_barrier(0);                                \
    __builtin_amdgcn_s_setprio(0);

#define RDA(BUF, MF0)                                                 \
    af0[0] = dsr<(MF0) * 2048>(aA##BUF##_0);                          \
    af0[1] = dsr<(MF0) * 2048>(aA##BUF##_1);                          \
    af1[0] = dsr<(MF0) * 2048 + 2048>(aA##BUF##_0);                   \
    af1[1] = dsr<(MF0) * 2048 + 2048>(aA##BUF##_1);

#define RDB(BUF, NF)                                                  \
    bfv[NF][0] = dsr<(NF) * 2048>(bB##BUF##_0);                       \
    bfv[NF][1] = dsr<(NF) * 2048>(bB##BUF##_1);

#define TILE(T, BUF, NB, AWE, AWO)                                              \
  {                                                                             \
    short8 bfv[4][2];                                                           \
    short8 af0[2], af1[2];                                                      \
    /* ---- phase 0: reads B(t)+A(t)mf01; issue A-gloads (t+1) ---- */          \
    RDB(BUF, 0) RDB(BUF, 1) RDB(BUF, 2) RDB(BUF, 3)                             \
    RDA(BUF, 0)                                                                 \
    AGLD((T) + 1)                                                               \
    PH_TAIL                                                                     \
    PH_MFMA(0)                                                                  \
    __builtin_amdgcn_s_barrier();                                               \
    /* ---- phase 1 ---- */                                                     \
    RDA(BUF, 2)                                                                 \
    STAGEB(NB, 0, (T) + 1); STAGEB(NB, 1, (T) + 1);                             \
    PH_TAIL                                                                     \
    PH_MFMA(2)                                                                  \
    __builtin_amdgcn_s_barrier();                                               \
    /* ---- phase 2 ---- */                                                     \
    RDA(BUF, 4)                                                                 \
    STAGEB(NB, 2, (T) + 1); STAGEB(NB, 3, (T) + 1);                             \
    PH_TAIL                                                                     \
    PH_MFMA(4)                                                                  \
    __builtin_amdgcn_s_barrier();                                               \
    /* ---- phase 3: convert+write A(t+1) -> nb; drain VM at tile end ---- */   \
    RDA(BUF, 6)                                                                 \
    CVTW(AWE, AWO)                                                              \
    PH_TAIL                                                                     \
    PH_MFMA(6)                                                                  \
    asm volatile("s_waitcnt vmcnt(0)" ::: "memory");                            \
    __builtin_amdgcn_sched_barrier(0);                                          \
    __builtin_amdgcn_s_barrier();                                               \
  }

    // ---- prologue: tile0 -> buf0 (A via reg-convert, B via DMA) ----
    AGLD(0)
    STAGEB(0, 0, 0); STAGEB(0, 1, 0); STAGEB(0, 2, 0); STAGEB(0, 3, 0);
    CVTW(awb0E, awb0O)
    asm volatile("s_waitcnt lgkmcnt(0)" ::: "memory");
    __builtin_amdgcn_sched_barrier(0);
    asm volatile("s_waitcnt vmcnt(0)" ::: "memory");
    __builtin_amdgcn_sched_barrier(0);
    __builtin_amdgcn_s_barrier();

    for (int t2 = 0; t2 < TK; t2 += 2) {
        TILE(t2,     0, 1, awb1E, awb1O)
        TILE(t2 + 1, 1, 0, awb0E, awb0O)
    }

    // ---- epilogue: bias + store (C/D: col=lane&15, row=(lane>>4)*4+r) ----
#pragma unroll
    for (int nf = 0; nf < 4; ++nf) {
        const int col = bn * 256 + wc * 64 + nf * 16 + (lane & 15);
        if (col < NDIM) {
            const float bv = bias[col];
#pragma unroll
            for (int mf = 0; mf < 8; ++mf) {
                const int row = bm * 256 + wr * 128 + mf * 16 + ((lane >> 4) << 2);
                float* op = out + (size_t)row * NDIM + col;
#pragma unroll
                for (int r = 0; r < 4; ++r)
                    op[(size_t)r * NDIM] = acc[mf][nf][r] + bv;
            }
        }
    }
#undef STAGEB
#undef AGLD
#undef CVT1
#undef CVTW
#undef PH_TAIL
#undef PH_MFMA
#undef RDA
#undef RDB
#undef TILE
}

// ---------------------------------------------------------------------------
// Fallback GEMM (static 64 KiB LDS, needs Xb) if dynamic-LDS attr fails
// ---------------------------------------------------------------------------
__global__ void gemm_bf_kernel(const unsigned short* __restrict__ Xb,
                               const unsigned short* __restrict__ Wt,
                               const float* __restrict__ bias,
                               float* __restrict__ out) {
    __shared__ __align__(16) unsigned short As[128][32];
    __shared__ __align__(16) unsigned short Bs[128][32];

    const int tid  = threadIdx.x;
    const int lane = tid & 63;
    const int wid  = tid >> 6;
    const int wr   = wid >> 1;
    const int wc   = wid & 1;
    const int bn   = blockIdx.x;
    const int bm   = blockIdx.y;

    f32x4 acc[4][4];
#pragma unroll
    for (int i = 0; i < 4; ++i)
#pragma unroll
        for (int j = 0; j < 4; ++j) {
            f32x4 z = {0.f, 0.f, 0.f, 0.f};
            acc[i][j] = z;
        }

    const unsigned short* abase =
        Xb + (size_t)(bm * 128 + wid * 16 + (lane >> 2)) * KDIM + (lane & 3) * 8;
    const unsigned short* bbase =
        Wt + (size_t)(bn * 128 + wid * 16 + (lane >> 2)) * KDIM + (lane & 3) * 8;

    for (int kt = 0; kt < KDIM; kt += 32) {
#pragma unroll
        for (int j = 0; j < 2; ++j)
            __builtin_amdgcn_global_load_lds(
                (const __attribute__((address_space(1))) unsigned int*)(abase + (size_t)j * 64 * KDIM + kt),
                (__attribute__((address_space(3))) unsigned int*)(&As[j * 64 + wid * 16][0]),
                16, 0, 0);
#pragma unroll
        for (int j = 0; j < 2; ++j)
            __builtin_amdgcn_global_load_lds(
                (const __attribute__((address_space(1))) unsigned int*)(bbase + (size_t)j * 64 * KDIM + kt),
                (__attribute__((address_space(3))) unsigned int*)(&Bs[j * 64 + wid * 16][0]),
                16, 0, 0);
        __syncthreads();

        short8 af[4], bfr[4];
#pragma unroll
        for (int mi = 0; mi < 4; ++mi)
            af[mi] = *(const short8*)&As[wr * 64 + mi * 16 + (lane & 15)][(lane >> 4) * 8];
#pragma unroll
        for (int ni = 0; ni < 4; ++ni)
            bfr[ni] = *(const short8*)&Bs[wc * 64 + ni * 16 + (lane & 15)][(lane >> 4) * 8];

#pragma unroll
        for (int mi = 0; mi < 4; ++mi)
#pragma unroll
            for (int ni = 0; ni < 4; ++ni)
                acc[mi][ni] = MFMA16(af[mi], bfr[ni], acc[mi][ni]);

        __syncthreads();
    }

#pragma unroll
    for (int ni = 0; ni < 4; ++ni) {
        const int col = bn * 128 + wc * 64 + ni * 16 + (lane & 15);
        if (col < NDIM) {
            const float bv = bias[col];
#pragma unroll
            for (int mi = 0; mi < 4; ++mi) {
                const int row = bm * 128 + wr * 64 + mi * 16 + ((lane >> 4) << 2);
                float* op = out + (size_t)row * NDIM + col;
#pragma unroll
                for (int r = 0; r < 4; ++r)
                    op[(size_t)r * NDIM] = acc[mi][ni][r] + bv;
            }
        }
    }
}

// ---------------------------------------------------------------------------
// Kernel 3: activation. One wave per (row, span of 51 cols).
// ---------------------------------------------------------------------------
__global__ void act_kernel(const float* __restrict__ outp,
                           const float* __restrict__ u,
                           float* __restrict__ dt) {
    const int lane  = threadIdx.x & 63;
    const int gwave = (blockIdx.x * 256 + threadIdx.x) >> 6;
    const int nwave = gridDim.x * 4;
    const int total = MDIM * 20;
    const float NEG_INF = -__builtin_inff();

    for (int unit = gwave; unit < total; unit += nwave) {
        const int row = unit / 20;
        const int sp  = unit - row * 20;
        const size_t base = (size_t)row * NDIM + sp * 51;

        float o = 0.f, uu = 0.5f;
        if (lane < 51) {
            o  = outp[base + lane];
            uu = u[base + lane];
        }
        const bool soft = (lane >= 1) && (lane < 51);

        const float uc = fmaxf(uu, 1e-9f);
        const float g  = -__logf(-__logf(uc));
        float z = soft ? (o + g) * 5.0f : NEG_INF;

        float m = z;
#pragma unroll
        for (int off = 32; off; off >>= 1) m = fmaxf(m, __shfl_xor(m, off));
        float e = soft ? __expf(z - m) : 0.f;
        float s = e;
#pragma unroll
        for (int off = 32; off; off >>= 1) s += __shfl_xor(s, off);

        float res;
        if (lane == 0) {
            const float ex = __expf(-2.0f * fabsf(o));
            const float t  = (1.0f - ex) / (1.0f + ex);
            res = copysignf(t, o);
        } else {
            res = e / s;
        }
        if (lane < 51) dt[base + lane] = res;
    }
}

// ---------------------------------------------------------------------------
extern "C" void kernel_launch(void* const* d_in, const int* in_sizes, int n_in,
                              void* d_out, int out_size, void* d_ws, size_t ws_size,
                              hipStream_t stream) {
    const float* x = (const float*)d_in[0];
    const float* W = (const float*)d_in[1];
    const float* b = (const float*)d_in[2];
    const float* u = (const float*)d_in[3];
    float* out = (float*)d_out;                      // outputs [M][N]
    float* dt  = out + (size_t)MDIM * NDIM;          // data_t  [M][N]
    unsigned short* Wt = (unsigned short*)d_ws;      // bf16 [NPAD][K], 4 MiB
    unsigned short* Xb = Wt + (size_t)NPAD * KDIM;   // fallback-only bf16 x

    prep_w_kernel<<<512, 256, 0, stream>>>(W, Wt);

    const hipError_t attr_ok = hipFuncSetAttribute(
        (const void*)gemm10_kernel, hipFuncAttributeMaxDynamicSharedMemorySize, 131072);
    if (attr_ok == hipSuccess) {
        gemm10_kernel<<<256, 512, 131072, stream>>>(x, Wt, b, out);
    } else {
        prep_x_kernel<<<2048, 256, 0, stream>>>(x, Xb);
        gemm_bf_kernel<<<dim3(8, 128), 256, 0, stream>>>(Xb, Wt, b, out);
    }

    act_kernel<<<8192, 256, 0, stream>>>(out, u, dt);
}